// Round 3
// baseline (5123.798 us; speedup 1.0000x reference)
//
#include <hip/hip_runtime.h>

#define BB 32
#define TT 64
#define NQl 128
#define HD 128
#define CPAD 524   // sC row stride (floats)
#define HPAD 132   // padded row stride for fp32 [32][128] tiles

typedef short bf16x8 __attribute__((ext_vector_type(8)));
typedef float f32x16 __attribute__((ext_vector_type(16)));

__device__ __forceinline__ unsigned short f2bf(float x) {
  unsigned int u = __float_as_uint(x);
  u += 0x7FFFu + ((u >> 16) & 1u);   // RNE
  return (unsigned short)(u >> 16);
}
__device__ __forceinline__ float bf2f(unsigned short h) {
  return __uint_as_float(((unsigned int)h) << 16);
}
__device__ __forceinline__ void f2bf_hl(float x, unsigned short& hi, unsigned short& lo) {
  hi = f2bf(x);
  lo = f2bf(x - bf2f(hi));   // residual capture: ~17-bit combined mantissa
}

__device__ __forceinline__ float sigmoidf_(float x) {
  return __builtin_amdgcn_rcpf(1.f + __expf(-x));
}
__device__ __forceinline__ float tanhf_(float x) {
  float a = fminf(fabsf(x), 15.f);
  float e = __expf(-2.f * a);
  float t = (1.f - e) * __builtin_amdgcn_rcpf(1.f + e);
  return copysignf(t, x);
}
__device__ __forceinline__ float dot4_(float4 a, float4 b) {
  return a.x * b.x + a.y * b.y + a.z * b.z + a.w * b.w;
}
__device__ __forceinline__ void pack_frag_hl(float4 a, float4 b, bf16x8& hi, bf16x8& lo) {
  float v[8] = {a.x, a.y, a.z, a.w, b.x, b.y, b.z, b.w};
#pragma unroll
  for (int i = 0; i < 8; ++i) {
    unsigned short h, l;
    f2bf_hl(v[i], h, l);
    hi[i] = (short)h; lo[i] = (short)l;
  }
}
__device__ __forceinline__ void pack8_hl(const float v[8], uint4& hi, uint4& lo) {
  unsigned short h[8], l[8];
#pragma unroll
  for (int i = 0; i < 8; ++i) f2bf_hl(v[i], h[i], l[i]);
  hi = make_uint4(h[0] | ((unsigned int)h[1] << 16), h[2] | ((unsigned int)h[3] << 16),
                  h[4] | ((unsigned int)h[5] << 16), h[6] | ((unsigned int)h[7] << 16));
  lo = make_uint4(l[0] | ((unsigned int)l[1] << 16), l[2] | ((unsigned int)l[3] << 16),
                  l[4] | ((unsigned int)l[5] << 16), l[6] | ((unsigned int)l[7] << 16));
}

// One workgroup per time step t.  512 threads = 8 waves.
// Wavefront pipeline: step (t,n) waits on flag(t-1,n); total depth T+NQ-1.
__global__ void __launch_bounds__(512, 2) gkt_wavefront(
    const int* __restrict__ qp, const int* __restrict__ rp_,
    const float* __restrict__ x_emb, const float* __restrict__ init_h,
    const float* __restrict__ w1, const float* __restrict__ b1,
    const float* __restrict__ w2, const float* __restrict__ b2,
    const float* __restrict__ w_ih, const float* __restrict__ w_hh,
    const float* __restrict__ b_ih, const float* __restrict__ b_hh,
    const float* __restrict__ bias, const float* __restrict__ out_w,
    float* __restrict__ y_out, float* h_out, int* flags, int* ticket) {
  // LDS ~152.6 KiB (<=160 KiB; 136.6 proven working in round 2)
  __shared__ __align__(16) unsigned char smAh[32 * 512];  // A-hi bf16 [32][256], XOR-swizzled
  __shared__ __align__(16) unsigned char smAl[32 * 512];  // A-lo residual
  __shared__ float sC[32 * CPAD];
  __shared__ float sHrun[32 * HPAD];
  __shared__ float sHtp[32 * HPAD];
  __shared__ float sXt[32 * HPAD];
  __shared__ float sRed[4 * HPAD];
  __shared__ float sV1[128], sV2[128];
  __shared__ float sBias[128], sOutW[128], sB1[128], sB2[128];
  __shared__ unsigned int sMask[128];
  __shared__ int sTicket;

  const int tid = threadIdx.x;
  const int lane = tid & 63;
  const int wv = tid >> 6;

  if (tid == 0) sTicket = atomicAdd(ticket, 1);
  __syncthreads();
  const int t = sTicket;

  if (tid < 128) {
    sBias[tid] = bias[tid];
    sOutW[tid] = out_w[tid];
    sB1[tid] = b1[tid];
    sB2[tid] = b2[tid];
    sMask[tid] = 0u;
  }
  for (int i = tid; i < 32 * HPAD; i += 512) sHrun[i] = 0.f;
  __syncthreads();
  if (tid < 32) {
    int qb = qp[tid * TT + t];
    atomicOr(&sMask[qb], 1u << tid);
  }
  {  // xt rows + zero A right half (h_run = 0) in both hi and lo
    const int b = tid >> 4, f = tid & 15;
    int qb = qp[b * TT + t];
    int rb = rp_[b * TT + t];
    const float* src = x_emb + (size_t)(qb + NQl * rb) * HD + f * 8;
    *(float4*)(sXt + b * HPAD + f * 8) = *(const float4*)src;
    *(float4*)(sXt + b * HPAD + f * 8 + 4) = *(const float4*)(src + 4);
    unsigned int zoff = (unsigned int)((256 + f * 16) ^ ((b & 7) << 4));
    *(uint4*)(smAh + b * 512 + zoff) = make_uint4(0, 0, 0, 0);
    *(uint4*)(smAl + b * 512 + zoff) = make_uint4(0, 0, 0, 0);
  }

  // ---- B fragments hi+lo (resident in VGPRs for the whole kernel) ----
  const int l31 = lane & 31;
  const int lhi = lane >> 5;
  const int gcol = wv * 32 + l31;  // r/z combined column, 0..255
  bf16x8 Brz[16], BrzL[16];
#pragma unroll
  for (int ks = 0; ks < 16; ++ks) {
    const float* src = (ks < 8)
        ? (w_ih + (size_t)gcol * 256 + 128 + ks * 16 + lhi * 8)   // ht half
        : (w_hh + (size_t)gcol * 128 + (ks - 8) * 16 + lhi * 8);  // h_run half
    pack_frag_hl(*(const float4*)src, *(const float4*)(src + 4), Brz[ks], BrzL[ks]);
  }
  const int ecol = (wv < 4) ? (256 + wv * 32 + l31) : (384 + (wv - 4) * 32 + l31);
  const int erow = (wv < 4) ? ecol : (ecol - 128);  // gate-row g in 256..383
  bf16x8 Bex[8], BexL[8];
#pragma unroll
  for (int ks = 0; ks < 8; ++ks) {
    const float* src = (wv < 4)
        ? (w_ih + (size_t)erow * 256 + 128 + ks * 16 + lhi * 8)  // inn (ht half)
        : (w_hh + (size_t)erow * 128 + ks * 16 + lhi * 8);       // hn (h_run half)
    pack_frag_hl(*(const float4*)src, *(const float4*)(src + 4), Bex[ks], BexL[ks]);
  }
  const float bias_rz = b_ih[gcol] + b_hh[gcol];
  const float bias_ex = (wv < 4) ? b_ih[ecol] : b_hh[erow];

  // ---- prologue: ht_prev[:, 0] ----
  {
    if (t > 0) {
      if (lane == 0) {
        int c = 0;
        while (__hip_atomic_load(&flags[(t - 1) * NQl + 0], __ATOMIC_RELAXED,
                                 __HIP_MEMORY_SCOPE_AGENT) == 0) {
          __builtin_amdgcn_s_sleep(1);
          if (++c > (1 << 20)) break;
        }
      }
      __builtin_amdgcn_fence(__ATOMIC_ACQUIRE, "agent");
    }
    const int b = tid >> 4, f = tid & 15;
    float v[8];
    if (t == 0) {
      const float* src = init_h + f * 8;
      *(float4*)&v[0] = *(const float4*)src;
      *(float4*)&v[4] = *(const float4*)(src + 4);
    } else {
      float* src = h_out + (((size_t)b * (TT + 1) + t) * NQl + 0) * HD + f * 8;
#pragma unroll
      for (int i = 0; i < 8; ++i)
        v[i] = __hip_atomic_load(src + i, __ATOMIC_RELAXED, __HIP_MEMORY_SCOPE_AGENT);
    }
#pragma unroll
    for (int i = 0; i < 8; ++i) sHtp[b * HPAD + f * 8 + i] = v[i];
    uint4 ph, pl;
    pack8_hl(v, ph, pl);
    unsigned int zoff = (unsigned int)((f * 16) ^ ((b & 7) << 4));
    *(uint4*)(smAh + b * 512 + zoff) = ph;
    *(uint4*)(smAl + b * 512 + zoff) = pl;
  }
  __syncthreads();

  const int rowbase = l31 * 512;
  const unsigned int swz = (unsigned int)((l31 & 7) << 4);

  for (int n = 0; n < NQl; ++n) {
    // ===== MFMA: [32,256] @ [256, 512-split], bf16 3-product emulation =====
    f32x16 accR, accE;
#pragma unroll
    for (int i = 0; i < 16; ++i) { accR[i] = bias_rz; accE[i] = bias_ex; }
#pragma unroll
    for (int ks = 0; ks < 16; ++ks) {
      unsigned int off = ((unsigned int)(ks * 32 + (lhi << 4))) ^ swz;
      bf16x8 avh = *(const bf16x8*)(smAh + rowbase + off);
      bf16x8 avl = *(const bf16x8*)(smAl + rowbase + off);
      accR = __builtin_amdgcn_mfma_f32_32x32x16_bf16(avh, Brz[ks], accR, 0, 0, 0);
      accR = __builtin_amdgcn_mfma_f32_32x32x16_bf16(avh, BrzL[ks], accR, 0, 0, 0);
      accR = __builtin_amdgcn_mfma_f32_32x32x16_bf16(avl, Brz[ks], accR, 0, 0, 0);
      if (wv < 4) {
        if (ks < 8) {
          accE = __builtin_amdgcn_mfma_f32_32x32x16_bf16(avh, Bex[ks], accE, 0, 0, 0);
          accE = __builtin_amdgcn_mfma_f32_32x32x16_bf16(avh, BexL[ks], accE, 0, 0, 0);
          accE = __builtin_amdgcn_mfma_f32_32x32x16_bf16(avl, Bex[ks], accE, 0, 0, 0);
        }
      } else {
        if (ks >= 8) {
          accE = __builtin_amdgcn_mfma_f32_32x32x16_bf16(avh, Bex[ks - 8], accE, 0, 0, 0);
          accE = __builtin_amdgcn_mfma_f32_32x32x16_bf16(avh, BexL[ks - 8], accE, 0, 0, 0);
          accE = __builtin_amdgcn_mfma_f32_32x32x16_bf16(avl, Bex[ks - 8], accE, 0, 0, 0);
        }
      }
    }
#pragma unroll
    for (int rg = 0; rg < 16; ++rg) {  // C layout: col=lane&31, row=(rg&3)+8*(rg>>2)+4*(lane>>5)
      int br = (rg & 3) + 8 * (rg >> 2) + 4 * lhi;
      sC[br * CPAD + gcol] = accR[rg];
      sC[br * CPAD + ecol] = accE[rg];
    }
    __syncthreads();

    // ===== prefetch ht_prev[:, n+1] =====
    const int nn = n + 1;
    float pf[8];
    if (nn < NQl) {
      if (t > 0) {
        if (lane == 0) {
          int c = 0;
          while (__hip_atomic_load(&flags[(t - 1) * NQl + nn], __ATOMIC_RELAXED,
                                   __HIP_MEMORY_SCOPE_AGENT) == 0) {
            __builtin_amdgcn_s_sleep(1);
            if (++c > (1 << 20)) break;
          }
        }
        __builtin_amdgcn_fence(__ATOMIC_ACQUIRE, "agent");
        const int b = tid >> 4, f = tid & 15;
        float* src = h_out + (((size_t)b * (TT + 1) + t) * NQl + nn) * HD + f * 8;
#pragma unroll
        for (int i = 0; i < 8; ++i)
          pf[i] = __hip_atomic_load(src + i, __ATOMIC_RELAXED, __HIP_MEMORY_SCOPE_AGENT);
      } else {
        const int f = tid & 15;
        const float* src = init_h + (size_t)nn * HD + f * 8;
        *(float4*)&pf[0] = *(const float4*)src;
        *(float4*)&pf[4] = *(const float4*)(src + 4);
      }
    }

    // ===== MLP correction for matched nodes (fp32, adds to gi cols 0..383) =====
    unsigned int mk = sMask[n];
    while (mk) {
      const int b0 = __ffs(mk) - 1;
      mk &= mk - 1;
      {
        const int j = tid & 127, kq = tid >> 7;
        const float* wr = w1 + (size_t)j * 256 + kq * 64;
        const float* xr = (kq < 2) ? (sHtp + b0 * HPAD + kq * 64)
                                   : (sXt + b0 * HPAD + (kq - 2) * 64);
        float s = 0.f;
#pragma unroll
        for (int ii = 0; ii < 16; ++ii)
          s += dot4_(*(const float4*)(wr + ii * 4), *(const float4*)(xr + ii * 4));
        sRed[kq * HPAD + j] = s;
      }
      __syncthreads();
      if (tid < 128) {
        float v = sB1[tid] + sRed[tid] + sRed[HPAD + tid] + sRed[2 * HPAD + tid] + sRed[3 * HPAD + tid];
        sV1[tid] = fmaxf(v, 0.f);
      }
      __syncthreads();
      {
        const int j = tid & 127, kq = tid >> 7;
        const float* wr = w2 + (size_t)j * 128 + kq * 32;
        const float* xr = sV1 + kq * 32;
        float s = 0.f;
#pragma unroll
        for (int ii = 0; ii < 8; ++ii)
          s += dot4_(*(const float4*)(wr + ii * 4), *(const float4*)(xr + ii * 4));
        sRed[kq * HPAD + j] = s;
      }
      __syncthreads();
      if (tid < 128)
        sV2[tid] = sB2[tid] + sRed[tid] + sRed[HPAD + tid] + sRed[2 * HPAD + tid] + sRed[3 * HPAD + tid];
      __syncthreads();
      if (tid < 384) {
        const float* wr = w_ih + (size_t)tid * 256;  // first 128 cols (m-part of u)
        float s = 0.f;
#pragma unroll
        for (int ii = 0; ii < 32; ++ii)
          s += dot4_(*(const float4*)(wr + ii * 4), *(const float4*)(sV2 + ii * 4));
        sC[b0 * CPAD + tid] += s;
      }
      __syncthreads();
    }

    // ===== gates + outputs (fp32) =====
    {
      const int b = tid >> 4;
      const int f = tid & 15;
      const int j0 = f * 8;
      const float* Cb = sC + b * CPAD;
      float rpre[8], zpre[8], ipre[8], hpre[8], hold[8];
      *(float4*)&rpre[0] = *(const float4*)(Cb + j0);
      *(float4*)&rpre[4] = *(const float4*)(Cb + j0 + 4);
      *(float4*)&zpre[0] = *(const float4*)(Cb + 128 + j0);
      *(float4*)&zpre[4] = *(const float4*)(Cb + 128 + j0 + 4);
      *(float4*)&ipre[0] = *(const float4*)(Cb + 256 + j0);
      *(float4*)&ipre[4] = *(const float4*)(Cb + 256 + j0 + 4);
      *(float4*)&hpre[0] = *(const float4*)(Cb + 384 + j0);
      *(float4*)&hpre[4] = *(const float4*)(Cb + 384 + j0 + 4);
      *(float4*)&hold[0] = *(const float4*)(sHrun + b * HPAD + j0);
      *(float4*)&hold[4] = *(const float4*)(sHrun + b * HPAD + j0 + 4);
      float hnew[8];
      float yp = 0.f;
#pragma unroll
      for (int i = 0; i < 8; ++i) {
        float rg = sigmoidf_(rpre[i]);
        float zg = sigmoidf_(zpre[i]);
        float ng = tanhf_(ipre[i] + rg * hpre[i]);
        float hv = ng + zg * (hold[i] - ng);
        hnew[i] = hv;
        yp += hv * sOutW[j0 + i];
      }
      *(float4*)(sHrun + b * HPAD + j0) = *(float4*)&hnew[0];
      *(float4*)(sHrun + b * HPAD + j0 + 4) = *(float4*)&hnew[4];
      uint4 ph, pl;
      pack8_hl(hnew, ph, pl);
      unsigned int zoff = (unsigned int)((256 + f * 16) ^ ((b & 7) << 4));
      *(uint4*)(smAh + b * 512 + zoff) = ph;
      *(uint4*)(smAl + b * 512 + zoff) = pl;
      float* hd = h_out + (((size_t)b * (TT + 1) + (t + 1)) * NQl + n) * HD + j0;
#pragma unroll
      for (int i = 0; i < 8; ++i)
        __hip_atomic_store(hd + i, hnew[i], __ATOMIC_RELAXED, __HIP_MEMORY_SCOPE_AGENT);
      if (t == 0) {  // h[:, 0] = init_h broadcast
        float* h0 = h_out + (((size_t)b * (TT + 1)) * NQl + n) * HD + j0;
        *(float4*)h0 = *(const float4*)(sHtp + b * HPAD + j0);
        *(float4*)(h0 + 4) = *(const float4*)(sHtp + b * HPAD + j0 + 4);
      }
      yp += __shfl_xor(yp, 1);
      yp += __shfl_xor(yp, 2);
      yp += __shfl_xor(yp, 4);
      yp += __shfl_xor(yp, 8);
      if (f == 0) {
        float yv = sigmoidf_(yp + sBias[n]);
        y_out[((size_t)b * TT + t) * NQl + n] = yv;
      }
    }

    // ===== land prefetched ht_prev[:, n+1] =====
    if (nn < NQl) {
      const int b = tid >> 4, f = tid & 15;
#pragma unroll
      for (int i = 0; i < 8; ++i) sHtp[b * HPAD + f * 8 + i] = pf[i];
      uint4 ph, pl;
      pack8_hl(pf, ph, pl);
      unsigned int zoff = (unsigned int)((f * 16) ^ ((b & 7) << 4));
      *(uint4*)(smAh + b * 512 + zoff) = ph;
      *(uint4*)(smAl + b * 512 + zoff) = pl;
    }
    __syncthreads();  // drains vmcnt(0): all agent-scope h stores complete
    if (tid == 0)
      __hip_atomic_store(&flags[t * NQl + n], 1, __ATOMIC_RELEASE, __HIP_MEMORY_SCOPE_AGENT);
  }
}

extern "C" void kernel_launch(void* const* d_in, const int* in_sizes, int n_in,
                              void* d_out, int out_size, void* d_ws, size_t ws_size,
                              hipStream_t stream) {
  (void)in_sizes; (void)n_in; (void)out_size; (void)ws_size;
  const int* q = (const int*)d_in[0];
  const int* r = (const int*)d_in[1];
  const float* x_emb = (const float*)d_in[2];
  // d_in[3] = q_emb: provably unused (only feeds masked-out MLP rows)
  const float* init_h = (const float*)d_in[4];
  const float* w1 = (const float*)d_in[5];
  const float* b1 = (const float*)d_in[6];
  const float* w2 = (const float*)d_in[7];
  const float* b2 = (const float*)d_in[8];
  const float* w_ih = (const float*)d_in[9];
  const float* w_hh = (const float*)d_in[10];
  const float* b_ih = (const float*)d_in[11];
  const float* b_hh = (const float*)d_in[12];
  const float* bias = (const float*)d_in[13];
  const float* out_w = (const float*)d_in[14];

  float* y_out = (float*)d_out;
  float* h_out = y_out + (size_t)BB * TT * NQl;  // 262144 floats of y, then h
  int* flags = (int*)d_ws;
  int* ticket = flags + TT * NQl;

  hipMemsetAsync(d_ws, 0, (TT * NQl + 16) * sizeof(int), stream);
  gkt_wavefront<<<TT, 512, 0, stream>>>(q, r, x_emb, init_h, w1, b1, w2, b2,
                                        w_ih, w_hh, b_ih, b_hh, bias, out_w,
                                        y_out, h_out, flags, ticket);
}

// Round 4
// 4530.899 us; speedup vs baseline: 1.1309x; 1.1309x over previous
//
#include <hip/hip_runtime.h>

#define BB 32
#define TT 64
#define NQl 128
#define HD 128
#define CPAD 524   // sC row stride (floats)
#define HPAD 132   // padded row stride for fp32 [32][128] tiles

typedef short bf16x8 __attribute__((ext_vector_type(8)));
typedef float f32x16 __attribute__((ext_vector_type(16)));
typedef float f32x4 __attribute__((ext_vector_type(4)));

__device__ __forceinline__ unsigned short f2bf(float x) {
  unsigned int u = __float_as_uint(x);
  u += 0x7FFFu + ((u >> 16) & 1u);   // RNE
  return (unsigned short)(u >> 16);
}
__device__ __forceinline__ float bf2f(unsigned short h) {
  return __uint_as_float(((unsigned int)h) << 16);
}
__device__ __forceinline__ void f2bf_hl(float x, unsigned short& hi, unsigned short& lo) {
  hi = f2bf(x);
  lo = f2bf(x - bf2f(hi));   // residual: ~17-bit combined mantissa
}
__device__ __forceinline__ float sigmoidf_(float x) {
  return __builtin_amdgcn_rcpf(1.f + __expf(-x));
}
__device__ __forceinline__ float tanhf_(float x) {
  float a = fminf(fabsf(x), 15.f);
  float e = __expf(-2.f * a);
  float t = (1.f - e) * __builtin_amdgcn_rcpf(1.f + e);
  return copysignf(t, x);
}
__device__ __forceinline__ float dot4_(f32x4 a, f32x4 b) {
  return a[0] * b[0] + a[1] * b[1] + a[2] * b[2] + a[3] * b[3];
}
__device__ __forceinline__ void pack_frag_hl(f32x4 a, f32x4 b, bf16x8& hi, bf16x8& lo) {
  float v[8] = {a[0], a[1], a[2], a[3], b[0], b[1], b[2], b[3]};
#pragma unroll
  for (int i = 0; i < 8; ++i) {
    unsigned short h, l;
    f2bf_hl(v[i], h, l);
    hi[i] = (short)h; lo[i] = (short)l;
  }
}
__device__ __forceinline__ void pack8_hl(const float v[8], uint4& hi, uint4& lo) {
  unsigned short h[8], l[8];
#pragma unroll
  for (int i = 0; i < 8; ++i) f2bf_hl(v[i], h[i], l[i]);
  hi = make_uint4(h[0] | ((unsigned int)h[1] << 16), h[2] | ((unsigned int)h[3] << 16),
                  h[4] | ((unsigned int)h[5] << 16), h[6] | ((unsigned int)h[7] << 16));
  lo = make_uint4(l[0] | ((unsigned int)l[1] << 16), l[2] | ((unsigned int)l[3] << 16),
                  l[4] | ((unsigned int)l[5] << 16), l[6] | ((unsigned int)l[7] << 16));
}

// ---- agent-coherent (sc1: IF$-level, cross-XCD) wide loads/stores ----
__device__ __forceinline__ void issue_load64_cc(const float* p, f32x4& a, f32x4& b,
                                                f32x4& c, f32x4& d) {
  asm volatile(
      "global_load_dwordx4 %0, %4, off sc1\n\t"
      "global_load_dwordx4 %1, %4, off offset:16 sc1\n\t"
      "global_load_dwordx4 %2, %4, off offset:32 sc1\n\t"
      "global_load_dwordx4 %3, %4, off offset:48 sc1"
      : "=&v"(a), "=&v"(b), "=&v"(c), "=&v"(d)
      : "v"(p) : "memory");
}
__device__ __forceinline__ void wait_vm0_4(f32x4& a, f32x4& b, f32x4& c, f32x4& d) {
  asm volatile("s_waitcnt vmcnt(0)" : "+v"(a), "+v"(b), "+v"(c), "+v"(d) :: "memory");
  __builtin_amdgcn_sched_barrier(0);
}
__device__ __forceinline__ void store32_cc(float* p, f32x4 a, f32x4 b) {
  asm volatile(
      "global_store_dwordx4 %0, %1, off sc1\n\t"
      "global_store_dwordx4 %0, %2, off offset:16 sc1"
      :: "v"(p), "v"(a), "v"(b) : "memory");
}

// MFMA chain: 3-product bf16 emulation, NS K-slots starting at S0 -> sC[:, OUTCOL]
#define CHAIN(NS, S0, FRH, FRL, BIASV, OUTCOL)                                   \
  {                                                                              \
    f32x16 acc;                                                                  \
    _Pragma("unroll")                                                            \
    for (int i = 0; i < 16; ++i) acc[i] = (BIASV);                               \
    _Pragma("unroll")                                                            \
    for (int ks = 0; ks < (NS); ++ks) {                                          \
      const int slot = (S0) + ks;                                                \
      unsigned int off = ((unsigned int)(slot * 32 + (lhi << 4))) ^ swz;         \
      bf16x8 avh = *(const bf16x8*)(smAh + rowbase + off);                       \
      bf16x8 avl = *(const bf16x8*)(smAl + rowbase + off);                       \
      acc = __builtin_amdgcn_mfma_f32_32x32x16_bf16(avh, FRH[ks], acc, 0, 0, 0); \
      acc = __builtin_amdgcn_mfma_f32_32x32x16_bf16(avh, FRL[ks], acc, 0, 0, 0); \
      acc = __builtin_amdgcn_mfma_f32_32x32x16_bf16(avl, FRH[ks], acc, 0, 0, 0); \
    }                                                                            \
    _Pragma("unroll")                                                            \
    for (int rg = 0; rg < 16; ++rg) {                                            \
      int br = (rg & 3) + 8 * (rg >> 2) + 4 * lhi;                               \
      sC[br * CPAD + (OUTCOL)] = acc[rg];                                        \
    }                                                                            \
  }

// One workgroup (256 threads = 4 waves, 1 wave/SIMD, 512-VGPR budget) per t.
__global__ void __launch_bounds__(256, 1) gkt_wavefront(
    const int* __restrict__ qp, const int* __restrict__ rp_,
    const float* __restrict__ x_emb, const float* __restrict__ init_h,
    const float* __restrict__ w1, const float* __restrict__ b1,
    const float* __restrict__ w2, const float* __restrict__ b2,
    const float* __restrict__ w_ih, const float* __restrict__ w_hh,
    const float* __restrict__ b_ih, const float* __restrict__ b_hh,
    const float* __restrict__ bias, const float* __restrict__ out_w,
    float* __restrict__ y_out, float* h_out, int* flags, int* ticket) {
  __shared__ __align__(16) unsigned char smAh[32 * 512];  // A-hi bf16 [32][256], swizzled
  __shared__ __align__(16) unsigned char smAl[32 * 512];  // A-lo residual
  __shared__ float sC[32 * CPAD];
  __shared__ float sHrun[32 * HPAD];
  __shared__ float sHtp[32 * HPAD];
  __shared__ float sXt[32 * HPAD];
  __shared__ float sRed[4 * HPAD];
  __shared__ float sV1[128], sV2[128];
  __shared__ float sBias[128], sOutW[128], sB1[128], sB2[128];
  __shared__ unsigned int sMask[128];
  __shared__ int sTicket;

  const int tid = threadIdx.x;
  const int lane = tid & 63;
  const int wv = tid >> 6;        // 0..3
  const int l31 = lane & 31;
  const int lhi = lane >> 5;

  if (tid == 0) sTicket = atomicAdd(ticket, 1);
  __syncthreads();
  const int t = sTicket;

  if (tid < 128) {
    sBias[tid] = bias[tid];
    sOutW[tid] = out_w[tid];
    sB1[tid] = b1[tid];
    sB2[tid] = b2[tid];
    sMask[tid] = 0u;
  }
  for (int i = tid; i < 32 * HPAD; i += 256) sHrun[i] = 0.f;
  __syncthreads();
  if (tid < 32) {
    int qb = qp[tid * TT + t];
    atomicOr(&sMask[qb], 1u << tid);
  }

  const int b = tid >> 3;          // batch 0..31
  const int f = tid & 7;           // 16-float slice
  const unsigned int swzb = (unsigned int)((b & 7) << 4);
  {  // xt rows (16 floats/thread) + zero A right half (h_run = 0)
    int qb = qp[b * TT + t];
    int rb = rp_[b * TT + t];
    const float* src = x_emb + (size_t)(qb + NQl * rb) * HD + f * 16;
#pragma unroll
    for (int c = 0; c < 4; ++c)
      *(f32x4*)(sXt + b * HPAD + f * 16 + c * 4) = *(const f32x4*)(src + c * 4);
#pragma unroll
    for (int hh = 0; hh < 2; ++hh) {
      unsigned int zoff = ((unsigned int)(256 + f * 32 + hh * 16)) ^ swzb;
      *(uint4*)(smAh + b * 512 + zoff) = make_uint4(0, 0, 0, 0);
      *(uint4*)(smAl + b * 512 + zoff) = make_uint4(0, 0, 0, 0);
    }
  }

  // ---- B fragments hi+lo, resident in VGPRs (96 frags = 384 VGPRs/wave) ----
  const int g0col = wv * 32 + l31;         // r/z group 0 (cols 0..127)
  const int g1col = 128 + wv * 32 + l31;   // r/z group 1 (cols 128..255)
  bf16x8 Brz0[16], Brz0L[16], Brz1[16], Brz1L[16];
#pragma unroll
  for (int ks = 0; ks < 16; ++ks) {
    const float* s0 = (ks < 8)
        ? (w_ih + (size_t)g0col * 256 + 128 + ks * 16 + lhi * 8)
        : (w_hh + (size_t)g0col * 128 + (ks - 8) * 16 + lhi * 8);
    pack_frag_hl(*(const f32x4*)s0, *(const f32x4*)(s0 + 4), Brz0[ks], Brz0L[ks]);
    const float* s1 = (ks < 8)
        ? (w_ih + (size_t)g1col * 256 + 128 + ks * 16 + lhi * 8)
        : (w_hh + (size_t)g1col * 128 + (ks - 8) * 16 + lhi * 8);
    pack_frag_hl(*(const f32x4*)s1, *(const f32x4*)(s1 + 4), Brz1[ks], Brz1L[ks]);
  }
  const int e0col = 256 + wv * 32 + l31;   // inn preact column
  const int e1col = 384 + wv * 32 + l31;   // hn preact column
  const int r1 = e1col - 128;              // w_hh row for hn (256..383)
  bf16x8 Bi[8], BiL[8], Bh[8], BhL[8];
#pragma unroll
  for (int ks = 0; ks < 8; ++ks) {
    const float* si = w_ih + (size_t)e0col * 256 + 128 + ks * 16 + lhi * 8;  // ht half
    pack_frag_hl(*(const f32x4*)si, *(const f32x4*)(si + 4), Bi[ks], BiL[ks]);
    const float* sh = w_hh + (size_t)r1 * 128 + ks * 16 + lhi * 8;           // h_run half
    pack_frag_hl(*(const f32x4*)sh, *(const f32x4*)(sh + 4), Bh[ks], BhL[ks]);
  }
  const float brz0 = b_ih[g0col] + b_hh[g0col];
  const float brz1 = b_ih[g1col] + b_hh[g1col];
  const float bi_b = b_ih[e0col];
  const float bh_b = b_hh[r1];

  // per-thread handoff pointers (64 B slice each)
  float* hstore_base = h_out + (((size_t)b * (TT + 1) + (t + 1)) * NQl) * HD + f * 16;
  const float* hload_base = h_out + (((size_t)b * (TT + 1) + t) * NQl) * HD + f * 16;

  // ---- prologue: ht_prev[:, 0] ----
  {
    float v[8 * 2];
    if (t > 0) {
      if (lane == 0) {
        int c = 0;
        while (__hip_atomic_load(&flags[(t - 1) * NQl + 0], __ATOMIC_RELAXED,
                                 __HIP_MEMORY_SCOPE_AGENT) == 0) {
          __builtin_amdgcn_s_sleep(1);
          if (++c > (1 << 20)) break;
        }
      }
      f32x4 a0, a1, a2, a3;
      issue_load64_cc(hload_base, a0, a1, a2, a3);
      wait_vm0_4(a0, a1, a2, a3);
      *(f32x4*)&v[0] = a0; *(f32x4*)&v[4] = a1;
      *(f32x4*)&v[8] = a2; *(f32x4*)&v[12] = a3;
    } else {
      const float* src = init_h + f * 16;
#pragma unroll
      for (int c = 0; c < 4; ++c) *(f32x4*)&v[c * 4] = *(const f32x4*)(src + c * 4);
    }
#pragma unroll
    for (int hh = 0; hh < 2; ++hh) {
      *(f32x4*)(sHtp + b * HPAD + f * 16 + hh * 8) = *(f32x4*)&v[hh * 8];
      *(f32x4*)(sHtp + b * HPAD + f * 16 + hh * 8 + 4) = *(f32x4*)&v[hh * 8 + 4];
      uint4 ph, pl;
      pack8_hl(&v[hh * 8], ph, pl);
      unsigned int zoff = ((unsigned int)(f * 32 + hh * 16)) ^ swzb;
      *(uint4*)(smAh + b * 512 + zoff) = ph;
      *(uint4*)(smAl + b * 512 + zoff) = pl;
    }
  }
  __syncthreads();

  const int rowbase = l31 * 512;
  const unsigned int swz = (unsigned int)((l31 & 7) << 4);

  for (int n = 0; n < NQl; ++n) {
    // ===== MFMA: [32,256] @ [256,512], per-wave 4 chains =====
    CHAIN(16, 0, Brz0, Brz0L, brz0, g0col)
    CHAIN(16, 0, Brz1, Brz1L, brz1, g1col)
    CHAIN(8, 0, Bi, BiL, bi_b, e0col)
    CHAIN(8, 8, Bh, BhL, bh_b, e1col)
    __syncthreads();

    // ===== MLP correction for matched nodes (fp32, adds to gi cols 0..383) =====
    unsigned int mk = sMask[n];
    while (mk) {
      const int b0 = __ffs(mk) - 1;
      mk &= mk - 1;
      {  // w1: 512 tasks (j x kq), 2 per thread
        const int j = tid & 127;
#pragma unroll
        for (int c = 0; c < 2; ++c) {
          const int kq = (tid >> 7) * 2 + c;
          const float* wr = w1 + (size_t)j * 256 + kq * 64;
          const float* xr = (kq < 2) ? (sHtp + b0 * HPAD + kq * 64)
                                     : (sXt + b0 * HPAD + (kq - 2) * 64);
          float s = 0.f;
#pragma unroll
          for (int ii = 0; ii < 16; ++ii)
            s += dot4_(*(const f32x4*)(wr + ii * 4), *(const f32x4*)(xr + ii * 4));
          sRed[kq * HPAD + j] = s;
        }
      }
      __syncthreads();
      if (tid < 128) {
        float v = sB1[tid] + sRed[tid] + sRed[HPAD + tid] + sRed[2 * HPAD + tid] +
                  sRed[3 * HPAD + tid];
        sV1[tid] = fmaxf(v, 0.f);
      }
      __syncthreads();
      {  // w2: 256 tasks (j x kq2), 1 per thread, 64-chunk each
        const int j = tid & 127, kq = tid >> 7;
        const float* wr = w2 + (size_t)j * 128 + kq * 64;
        const float* xr = sV1 + kq * 64;
        float s = 0.f;
#pragma unroll
        for (int ii = 0; ii < 16; ++ii)
          s += dot4_(*(const f32x4*)(wr + ii * 4), *(const f32x4*)(xr + ii * 4));
        sRed[kq * HPAD + j] = s;
      }
      __syncthreads();
      if (tid < 128) sV2[tid] = sB2[tid] + sRed[tid] + sRed[HPAD + tid];
      __syncthreads();
      for (int row = tid; row < 384; row += 256) {  // w_ih[:,0:128] @ mlp_out
        const float* wr = w_ih + (size_t)row * 256;
        float s = 0.f;
#pragma unroll
        for (int ii = 0; ii < 32; ++ii)
          s += dot4_(*(const f32x4*)(wr + ii * 4), *(const f32x4*)(sV2 + ii * 4));
        sC[b0 * CPAD + row] += s;
      }
      __syncthreads();
    }

    // ===== gates + outputs (fp32), 16 h-elems per thread in 2 halves =====
    {
      const float* Cb = sC + b * CPAD;
      float ypart = 0.f;
#pragma unroll
      for (int hh = 0; hh < 2; ++hh) {
        const int j0 = f * 16 + hh * 8;
        float rpre[8], zpre[8], ipre[8], hpre[8], hold[8];
        *(f32x4*)&rpre[0] = *(const f32x4*)(Cb + j0);
        *(f32x4*)&rpre[4] = *(const f32x4*)(Cb + j0 + 4);
        *(f32x4*)&zpre[0] = *(const f32x4*)(Cb + 128 + j0);
        *(f32x4*)&zpre[4] = *(const f32x4*)(Cb + 128 + j0 + 4);
        *(f32x4*)&ipre[0] = *(const f32x4*)(Cb + 256 + j0);
        *(f32x4*)&ipre[4] = *(const f32x4*)(Cb + 256 + j0 + 4);
        *(f32x4*)&hpre[0] = *(const f32x4*)(Cb + 384 + j0);
        *(f32x4*)&hpre[4] = *(const f32x4*)(Cb + 384 + j0 + 4);
        *(f32x4*)&hold[0] = *(const f32x4*)(sHrun + b * HPAD + j0);
        *(f32x4*)&hold[4] = *(const f32x4*)(sHrun + b * HPAD + j0 + 4);
        float hnew[8];
#pragma unroll
        for (int i = 0; i < 8; ++i) {
          float rg = sigmoidf_(rpre[i]);
          float zg = sigmoidf_(zpre[i]);
          float ng = tanhf_(ipre[i] + rg * hpre[i]);
          float hv = ng + zg * (hold[i] - ng);
          hnew[i] = hv;
          ypart += hv * sOutW[j0 + i];
        }
        *(f32x4*)(sHrun + b * HPAD + j0) = *(f32x4*)&hnew[0];
        *(f32x4*)(sHrun + b * HPAD + j0 + 4) = *(f32x4*)&hnew[4];
        uint4 ph, pl;
        pack8_hl(hnew, ph, pl);
        unsigned int zoff = ((unsigned int)(256 + f * 32 + hh * 16)) ^ swzb;
        *(uint4*)(smAh + b * 512 + zoff) = ph;
        *(uint4*)(smAl + b * 512 + zoff) = pl;
        store32_cc(hstore_base + (size_t)n * HD + hh * 8,
                   *(f32x4*)&hnew[0], *(f32x4*)&hnew[4]);
        if (t == 0) {  // h[:,0] = init_h broadcast (plain cached stores)
          float* h0 = h_out + (((size_t)b * (TT + 1)) * NQl + n) * HD + j0;
          *(f32x4*)h0 = *(const f32x4*)(sHtp + b * HPAD + j0);
          *(f32x4*)(h0 + 4) = *(const f32x4*)(sHtp + b * HPAD + j0 + 4);
        }
      }
      ypart += __shfl_xor(ypart, 1);
      ypart += __shfl_xor(ypart, 2);
      ypart += __shfl_xor(ypart, 4);
      if (f == 0) {
        float yv = sigmoidf_(ypart + sBias[n]);
        y_out[((size_t)b * TT + t) * NQl + n] = yv;
      }
    }

    // ===== poll + fetch ht_prev[:, n+1] (late poll: maximize producer overlap) =====
    const int nn = n + 1;
    if (nn < NQl) {
      f32x4 p0, p1, p2, p3;
      if (t > 0) {
        if (lane == 0) {
          int c = 0;
          while (__hip_atomic_load(&flags[(t - 1) * NQl + nn], __ATOMIC_RELAXED,
                                   __HIP_MEMORY_SCOPE_AGENT) == 0) {
            __builtin_amdgcn_s_sleep(1);
            if (++c > (1 << 20)) break;
          }
        }
        issue_load64_cc(hload_base + (size_t)nn * HD, p0, p1, p2, p3);
        wait_vm0_4(p0, p1, p2, p3);
      } else {
        const float* src = init_h + (size_t)nn * HD + f * 16;
        p0 = *(const f32x4*)src; p1 = *(const f32x4*)(src + 4);
        p2 = *(const f32x4*)(src + 8); p3 = *(const f32x4*)(src + 12);
      }
      // land into sHtp + smA left half
      float v[8];
#pragma unroll
      for (int hh = 0; hh < 2; ++hh) {
        f32x4 lo4 = (hh == 0) ? p0 : p2;
        f32x4 hi4 = (hh == 0) ? p1 : p3;
        *(f32x4*)&v[0] = lo4; *(f32x4*)&v[4] = hi4;
        *(f32x4*)(sHtp + b * HPAD + f * 16 + hh * 8) = lo4;
        *(f32x4*)(sHtp + b * HPAD + f * 16 + hh * 8 + 4) = hi4;
        uint4 ph, pl;
        pack8_hl(v, ph, pl);
        unsigned int zoff = ((unsigned int)(f * 32 + hh * 16)) ^ swzb;
        *(uint4*)(smAh + b * 512 + zoff) = ph;
        *(uint4*)(smAl + b * 512 + zoff) = pl;
      }
    }
    asm volatile("s_waitcnt vmcnt(0)" ::: "memory");  // all h-stores at IF$
    __syncthreads();
    if (tid == 0)
      __hip_atomic_store(&flags[t * NQl + n], 1, __ATOMIC_RELAXED,
                         __HIP_MEMORY_SCOPE_AGENT);
  }
}

extern "C" void kernel_launch(void* const* d_in, const int* in_sizes, int n_in,
                              void* d_out, int out_size, void* d_ws, size_t ws_size,
                              hipStream_t stream) {
  (void)in_sizes; (void)n_in; (void)out_size; (void)ws_size;
  const int* q = (const int*)d_in[0];
  const int* r = (const int*)d_in[1];
  const float* x_emb = (const float*)d_in[2];
  // d_in[3] = q_emb: provably unused (only feeds masked-out MLP rows)
  const float* init_h = (const float*)d_in[4];
  const float* w1 = (const float*)d_in[5];
  const float* b1 = (const float*)d_in[6];
  const float* w2 = (const float*)d_in[7];
  const float* b2 = (const float*)d_in[8];
  const float* w_ih = (const float*)d_in[9];
  const float* w_hh = (const float*)d_in[10];
  const float* b_ih = (const float*)d_in[11];
  const float* b_hh = (const float*)d_in[12];
  const float* bias = (const float*)d_in[13];
  const float* out_w = (const float*)d_in[14];

  float* y_out = (float*)d_out;
  float* h_out = y_out + (size_t)BB * TT * NQl;  // y first, then h
  int* flags = (int*)d_ws;
  int* ticket = flags + TT * NQl;

  hipMemsetAsync(d_ws, 0, (TT * NQl + 16) * sizeof(int), stream);
  gkt_wavefront<<<TT, 256, 0, stream>>>(q, r, x_emb, init_h, w1, b1, w2, b2,
                                        w_ih, w_hh, b_ih, b_hh, bias, out_w,
                                        y_out, h_out, flags, ticket);
}

// Round 5
// 2652.700 us; speedup vs baseline: 1.9315x; 1.7080x over previous
//
#include <hip/hip_runtime.h>

#define BB 32
#define TT 64
#define NQl 128
#define HD 128
#define CPAD 524   // sC row stride (floats)
#define HPAD 132   // padded row stride for fp32 [32][128] tiles

typedef _Float16 f16x8 __attribute__((ext_vector_type(8)));
typedef float f32x16 __attribute__((ext_vector_type(16)));
typedef float f32x4 __attribute__((ext_vector_type(4)));

__device__ __forceinline__ float sigmoidf_(float x) {
  return __builtin_amdgcn_rcpf(1.f + __expf(-x));
}
__device__ __forceinline__ float tanhf_(float x) {
  float a = fminf(fabsf(x), 15.f);
  float e = __expf(-2.f * a);
  float t = (1.f - e) * __builtin_amdgcn_rcpf(1.f + e);
  return copysignf(t, x);
}
__device__ __forceinline__ float dot4_(f32x4 a, f32x4 b) {
  return a[0] * b[0] + a[1] * b[1] + a[2] * b[2] + a[3] * b[3];
}
__device__ __forceinline__ f16x8 pack_frag_h(f32x4 a, f32x4 b) {
  f16x8 o;
  o[0] = (_Float16)a[0]; o[1] = (_Float16)a[1];
  o[2] = (_Float16)a[2]; o[3] = (_Float16)a[3];
  o[4] = (_Float16)b[0]; o[5] = (_Float16)b[1];
  o[6] = (_Float16)b[2]; o[7] = (_Float16)b[3];
  return o;
}
__device__ __forceinline__ uint4 pack8_h(const float v[8]) {
  union { f16x8 h; uint4 u; } c;
#pragma unroll
  for (int i = 0; i < 8; ++i) c.h[i] = (_Float16)v[i];
  return c.u;
}

// ---- agent-coherent (sc1: cross-XCD via IF$) wide loads/stores ----
__device__ __forceinline__ void issue_load32_cc(const float* p, f32x4& a, f32x4& b) {
  asm volatile(
      "global_load_dwordx4 %0, %2, off sc1\n\t"
      "global_load_dwordx4 %1, %2, off offset:16 sc1"
      : "=&v"(a), "=&v"(b) : "v"(p) : "memory");
}
__device__ __forceinline__ void wait_vm0_2(f32x4& a, f32x4& b) {
  asm volatile("s_waitcnt vmcnt(0)" : "+v"(a), "+v"(b) :: "memory");
  __builtin_amdgcn_sched_barrier(0);
}
__device__ __forceinline__ void store32_cc(float* p, f32x4 a, f32x4 b) {
  asm volatile(
      "global_store_dwordx4 %0, %1, off sc1\n\t"
      "global_store_dwordx4 %0, %2, off offset:16 sc1"
      :: "v"(p), "v"(a), "v"(b) : "memory");
}

// fp16 single-product MFMA chain over NS K-slots starting at S0 -> sC[:, OUTCOL]
#define CHAIN(NS, S0, FR, BIASV, OUTCOL)                                        \
  {                                                                             \
    f32x16 acc;                                                                 \
    _Pragma("unroll")                                                           \
    for (int i = 0; i < 16; ++i) acc[i] = (BIASV);                              \
    _Pragma("unroll")                                                           \
    for (int ks = 0; ks < (NS); ++ks) {                                         \
      unsigned int off = ((unsigned int)(((S0) + ks) * 32 + (lhi << 4))) ^ swz; \
      f16x8 av = *(const f16x8*)(smA + rowbase + off);                          \
      acc = __builtin_amdgcn_mfma_f32_32x32x16_f16(av, FR[ks], acc, 0, 0, 0);   \
    }                                                                           \
    _Pragma("unroll")                                                           \
    for (int rg = 0; rg < 16; ++rg) {                                           \
      int br = (rg & 3) + 8 * (rg >> 2) + 4 * lhi;                              \
      sC[br * CPAD + (OUTCOL)] = acc[rg];                                       \
    }                                                                           \
  }

// One workgroup (512 threads = 8 waves) per time step t.
// Wavefront pipeline: step (t,n) consumes flag(t-1,n); depth T+NQ-1.
__global__ void __launch_bounds__(512, 2) gkt_wavefront(
    const int* __restrict__ qp, const int* __restrict__ rp_,
    const float* __restrict__ x_emb, const float* __restrict__ init_h,
    const float* __restrict__ w1, const float* __restrict__ b1,
    const float* __restrict__ w2, const float* __restrict__ b2,
    const float* __restrict__ w_ih, const float* __restrict__ w_hh,
    const float* __restrict__ b_ih, const float* __restrict__ b_hh,
    const float* __restrict__ bias, const float* __restrict__ out_w,
    float* __restrict__ y_out, float* h_out, int* flags, int* ticket) {
  // LDS ~123 KiB
  __shared__ __align__(16) unsigned char smA[32 * 512];  // A=[ht_prev|h_run] fp16 [32][256], swizzled
  __shared__ float sC[32 * CPAD];
  __shared__ float sHrun[32 * HPAD];
  __shared__ float sHtp[32 * HPAD];
  __shared__ float sXt[32 * HPAD];
  __shared__ float sRed[4 * HPAD];
  __shared__ float sV1[128], sV2[128];
  __shared__ float sBias[128], sOutW[128], sB1[128], sB2[128];
  __shared__ unsigned int sMask[128];
  __shared__ int sTicket;

  const int tid = threadIdx.x;
  const int lane = tid & 63;
  const int wv = tid >> 6;        // 0..7
  const int l31 = lane & 31;
  const int lhi = lane >> 5;

  if (tid == 0) sTicket = atomicAdd(ticket, 1);
  __syncthreads();
  const int t = sTicket;

  if (tid < 128) {
    sBias[tid] = bias[tid];
    sOutW[tid] = out_w[tid];
    sB1[tid] = b1[tid];
    sB2[tid] = b2[tid];
    sMask[tid] = 0u;
  }
  for (int i = tid; i < 32 * HPAD; i += 512) sHrun[i] = 0.f;
  __syncthreads();
  if (tid < 32) {
    int qb = qp[tid * TT + t];
    atomicOr(&sMask[qb], 1u << tid);
  }

  const int b = tid >> 4;          // batch 0..31
  const int f = tid & 15;          // 8-float slice
  const unsigned int swzb = (unsigned int)((b & 7) << 4);
  {  // xt rows + zero A right half (h_run = 0)
    int qb = qp[b * TT + t];
    int rb = rp_[b * TT + t];
    const float* src = x_emb + (size_t)(qb + NQl * rb) * HD + f * 8;
    *(f32x4*)(sXt + b * HPAD + f * 8) = *(const f32x4*)src;
    *(f32x4*)(sXt + b * HPAD + f * 8 + 4) = *(const f32x4*)(src + 4);
    *(uint4*)(smA + b * 512 + ((unsigned int)(256 + f * 16) ^ swzb)) = make_uint4(0, 0, 0, 0);
  }

  // ---- B fragments fp16, resident (24 frags = 96 VGPRs/wave) ----
  const int gcol = wv * 32 + l31;  // r/z column 0..255
  f16x8 Brz[16];
#pragma unroll
  for (int ks = 0; ks < 16; ++ks) {
    const float* src = (ks < 8)
        ? (w_ih + (size_t)gcol * 256 + 128 + ks * 16 + lhi * 8)   // ht half
        : (w_hh + (size_t)gcol * 128 + (ks - 8) * 16 + lhi * 8);  // h_run half
    Brz[ks] = pack_frag_h(*(const f32x4*)src, *(const f32x4*)(src + 4));
  }
  const int ecol = (wv < 4) ? (256 + wv * 32 + l31) : (384 + (wv - 4) * 32 + l31);
  const int erow = (wv < 4) ? ecol : (ecol - 128);  // w_hh row for hn
  f16x8 Bex[8];
#pragma unroll
  for (int ks = 0; ks < 8; ++ks) {
    const float* src = (wv < 4)
        ? (w_ih + (size_t)erow * 256 + 128 + ks * 16 + lhi * 8)  // inn (ht half)
        : (w_hh + (size_t)erow * 128 + ks * 16 + lhi * 8);       // hn (h_run half)
    Bex[ks] = pack_frag_h(*(const f32x4*)src, *(const f32x4*)(src + 4));
  }
  const float brz = b_ih[gcol] + b_hh[gcol];
  const float bex = (wv < 4) ? b_ih[ecol] : b_hh[erow];

  // handoff pointers (32 B slice per thread)
  float* hstore_base = h_out + (((size_t)b * (TT + 1) + (t + 1)) * NQl) * HD + f * 8;
  const float* hload_base = h_out + (((size_t)b * (TT + 1) + t) * NQl) * HD + f * 8;

  // ---- t==0: bulk h[:,0,:,:] = init_h broadcast (hoisted out of loop) ----
  if (t == 0) {
    const f32x4* s4 = (const f32x4*)init_h;                  // 4096 vec4
    for (int i = tid; i < 32 * 4096; i += 512) {
      int bb = i >> 12, rem = i & 4095;
      ((f32x4*)(h_out + ((size_t)bb * (TT + 1)) * NQl * HD))[rem] = s4[rem];
    }
  }

  // ---- prologue: ht_prev[:, 0] ----
  {
    float v[8];
    if (t > 0) {
      if (lane == 0) {
        int c = 0;
        while (__hip_atomic_load(&flags[(t - 1) * NQl + 0], __ATOMIC_RELAXED,
                                 __HIP_MEMORY_SCOPE_AGENT) == 0) {
          __builtin_amdgcn_s_sleep(1);
          if (++c > (1 << 20)) break;
        }
      }
      f32x4 a0, a1;
      issue_load32_cc(hload_base, a0, a1);
      wait_vm0_2(a0, a1);
      *(f32x4*)&v[0] = a0; *(f32x4*)&v[4] = a1;
    } else {
      const float* src = init_h + f * 8;
      *(f32x4*)&v[0] = *(const f32x4*)src;
      *(f32x4*)&v[4] = *(const f32x4*)(src + 4);
    }
    *(f32x4*)(sHtp + b * HPAD + f * 8) = *(f32x4*)&v[0];
    *(f32x4*)(sHtp + b * HPAD + f * 8 + 4) = *(f32x4*)&v[4];
    *(uint4*)(smA + b * 512 + ((unsigned int)(f * 16) ^ swzb)) = pack8_h(v);
  }
  __syncthreads();

  const int rowbase = l31 * 512;
  const unsigned int swz = (unsigned int)((l31 & 7) << 4);

  for (int n = 0; n < NQl; ++n) {
    // ===== MFMA: [32,256] @ [256,512], fp16 single product =====
    CHAIN(16, 0, Brz, brz, gcol)
    if (wv < 4) { CHAIN(8, 0, Bex, bex, ecol) } else { CHAIN(8, 8, Bex, bex, ecol) }
    __syncthreads();

    // ===== MLP correction for matched nodes (fp32, adds to gi cols 0..383) =====
    unsigned int mk = sMask[n];
    while (mk) {
      const int b0 = __ffs(mk) - 1;
      mk &= mk - 1;
      {
        const int j = tid & 127, kq = tid >> 7;
        const float* wr = w1 + (size_t)j * 256 + kq * 64;
        const float* xr = (kq < 2) ? (sHtp + b0 * HPAD + kq * 64)
                                   : (sXt + b0 * HPAD + (kq - 2) * 64);
        float s = 0.f;
#pragma unroll
        for (int ii = 0; ii < 16; ++ii)
          s += dot4_(*(const f32x4*)(wr + ii * 4), *(const f32x4*)(xr + ii * 4));
        sRed[kq * HPAD + j] = s;
      }
      __syncthreads();
      if (tid < 128) {
        float v = sB1[tid] + sRed[tid] + sRed[HPAD + tid] + sRed[2 * HPAD + tid] +
                  sRed[3 * HPAD + tid];
        sV1[tid] = fmaxf(v, 0.f);
      }
      __syncthreads();
      {
        const int j = tid & 127, kq = tid >> 7;
        const float* wr = w2 + (size_t)j * 128 + kq * 32;
        const float* xr = sV1 + kq * 32;
        float s = 0.f;
#pragma unroll
        for (int ii = 0; ii < 8; ++ii)
          s += dot4_(*(const f32x4*)(wr + ii * 4), *(const f32x4*)(xr + ii * 4));
        sRed[kq * HPAD + j] = s;
      }
      __syncthreads();
      if (tid < 128)
        sV2[tid] = sB2[tid] + sRed[tid] + sRed[HPAD + tid] + sRed[2 * HPAD + tid] +
                   sRed[3 * HPAD + tid];
      __syncthreads();
      if (tid < 384) {
        const float* wr = w_ih + (size_t)tid * 256;  // m-columns (first 128)
        float s = 0.f;
#pragma unroll
        for (int ii = 0; ii < 32; ++ii)
          s += dot4_(*(const f32x4*)(wr + ii * 4), *(const f32x4*)(sV2 + ii * 4));
        sC[b0 * CPAD + tid] += s;
      }
      __syncthreads();
    }

    // ===== poll + ISSUE ht_prev[:, n+1] loads (latency hides under gates) =====
    const int nn = n + 1;
    f32x4 p0, p1;
    if (nn < NQl) {
      if (t > 0) {
        if (lane == 0) {
          int c = 0;
          while (__hip_atomic_load(&flags[(t - 1) * NQl + nn], __ATOMIC_RELAXED,
                                   __HIP_MEMORY_SCOPE_AGENT) == 0) {
            __builtin_amdgcn_s_sleep(1);
            if (++c > (1 << 20)) break;
          }
        }
        issue_load32_cc(hload_base + (size_t)nn * HD, p0, p1);
      } else {
        const float* src = init_h + (size_t)nn * HD + f * 8;
        p0 = *(const f32x4*)src;
        p1 = *(const f32x4*)(src + 4);
      }
    }

    // ===== gates + outputs (fp32), 8 h-elems per thread =====
    {
      const int j0 = f * 8;
      const float* Cb = sC + b * CPAD;
      float rpre[8], zpre[8], ipre[8], hpre[8], hold[8];
      *(f32x4*)&rpre[0] = *(const f32x4*)(Cb + j0);
      *(f32x4*)&rpre[4] = *(const f32x4*)(Cb + j0 + 4);
      *(f32x4*)&zpre[0] = *(const f32x4*)(Cb + 128 + j0);
      *(f32x4*)&zpre[4] = *(const f32x4*)(Cb + 128 + j0 + 4);
      *(f32x4*)&ipre[0] = *(const f32x4*)(Cb + 256 + j0);
      *(f32x4*)&ipre[4] = *(const f32x4*)(Cb + 256 + j0 + 4);
      *(f32x4*)&hpre[0] = *(const f32x4*)(Cb + 384 + j0);
      *(f32x4*)&hpre[4] = *(const f32x4*)(Cb + 384 + j0 + 4);
      *(f32x4*)&hold[0] = *(const f32x4*)(sHrun + b * HPAD + j0);
      *(f32x4*)&hold[4] = *(const f32x4*)(sHrun + b * HPAD + j0 + 4);
      float hnew[8];
      float yp = 0.f;
#pragma unroll
      for (int i = 0; i < 8; ++i) {
        float rg = sigmoidf_(rpre[i]);
        float zg = sigmoidf_(zpre[i]);
        float ng = tanhf_(ipre[i] + rg * hpre[i]);
        float hv = ng + zg * (hold[i] - ng);
        hnew[i] = hv;
        yp += hv * sOutW[j0 + i];
      }
      *(f32x4*)(sHrun + b * HPAD + j0) = *(f32x4*)&hnew[0];
      *(f32x4*)(sHrun + b * HPAD + j0 + 4) = *(f32x4*)&hnew[4];
      *(uint4*)(smA + b * 512 + ((unsigned int)(256 + f * 16) ^ swzb)) = pack8_h(hnew);
      store32_cc(hstore_base + (size_t)n * HD, *(f32x4*)&hnew[0], *(f32x4*)&hnew[4]);
      yp += __shfl_xor(yp, 1);
      yp += __shfl_xor(yp, 2);
      yp += __shfl_xor(yp, 4);
      yp += __shfl_xor(yp, 8);
      if (f == 0) {
        float yv = sigmoidf_(yp + sBias[n]);
        y_out[((size_t)b * TT + t) * NQl + n] = yv;
      }
    }

    // ===== land prefetched ht_prev[:, n+1] =====
    if (nn < NQl) {
      if (t > 0) wait_vm0_2(p0, p1);
      float v[8];
      *(f32x4*)&v[0] = p0; *(f32x4*)&v[4] = p1;
      *(f32x4*)(sHtp + b * HPAD + f * 8) = p0;
      *(f32x4*)(sHtp + b * HPAD + f * 8 + 4) = p1;
      *(uint4*)(smA + b * 512 + ((unsigned int)(f * 16) ^ swzb)) = pack8_h(v);
    }
    asm volatile("s_waitcnt vmcnt(0)" ::: "memory");  // h-stores visible at IF$
    __syncthreads();
    if (tid == 0)
      __hip_atomic_store(&flags[t * NQl + n], 1, __ATOMIC_RELAXED,
                         __HIP_MEMORY_SCOPE_AGENT);
  }
}

extern "C" void kernel_launch(void* const* d_in, const int* in_sizes, int n_in,
                              void* d_out, int out_size, void* d_ws, size_t ws_size,
                              hipStream_t stream) {
  (void)in_sizes; (void)n_in; (void)out_size; (void)ws_size;
  const int* q = (const int*)d_in[0];
  const int* r = (const int*)d_in[1];
  const float* x_emb = (const float*)d_in[2];
  // d_in[3] = q_emb: provably unused (only feeds masked-out MLP rows)
  const float* init_h = (const float*)d_in[4];
  const float* w1 = (const float*)d_in[5];
  const float* b1 = (const float*)d_in[6];
  const float* w2 = (const float*)d_in[7];
  const float* b2 = (const float*)d_in[8];
  const float* w_ih = (const float*)d_in[9];
  const float* w_hh = (const float*)d_in[10];
  const float* b_ih = (const float*)d_in[11];
  const float* b_hh = (const float*)d_in[12];
  const float* bias = (const float*)d_in[13];
  const float* out_w = (const float*)d_in[14];

  float* y_out = (float*)d_out;
  float* h_out = y_out + (size_t)BB * TT * NQl;  // y first, then h
  int* flags = (int*)d_ws;
  int* ticket = flags + TT * NQl;

  hipMemsetAsync(d_ws, 0, (TT * NQl + 16) * sizeof(int), stream);
  gkt_wavefront<<<TT, 512, 0, stream>>>(q, r, x_emb, init_h, w1, b1, w2, b2,
                                        w_ih, w_hh, b_ih, b_hh, bias, out_w,
                                        y_out, h_out, flags, ticket);
}